// Round 15
// baseline (65.069 us; speedup 1.0000x reference)
//
#include <hip/hip_runtime.h>

// B=4096, S=50, D=32, H=4, HD=8. ONE WAVE = ONE BATCH. 1024 blocks x 256 thr (4 waves).
// One __syncthreads total. W/bias direct from global (L1-hot); K2/q/P/ctx in registers
// (projR output layout == MFMA A/B fragment layout, HW-verified r12/r13); V2t + mask
// ballots in per-wave LDS. Softmax with max-subtraction: all outputs finite by design.
#define NB 4096
// fold 1/sqrt(8)*log2(e) into q: softmax uses raw v_exp_f32 (=2^x)
constexpr float kQscale = 0.35355339059327378f * 1.4426950408889634f;
constexpr int SV = 72;     // V2t stride [d][j] (shorts)

typedef __attribute__((ext_vector_type(8))) short bf16x8;
typedef __attribute__((ext_vector_type(4))) float f32x4;
typedef __attribute__((ext_vector_type(4))) unsigned u32x4;

__device__ __forceinline__ unsigned cvt2(float lo, float hi) {  // 2xf32 -> packed bf16 RNE
  unsigned u;
  asm("v_cvt_pk_bf16_f32 %0, %1, %2" : "=v"(u) : "v"(lo), "v"(hi));
  return u;
}
__device__ __forceinline__ float fexp2(float x) {               // 2^x, 1 inst
  float r;
  asm("v_exp_f32 %0, %1" : "=v"(r) : "v"(x));
  return r;
}
// xchF(a,b): P32(dst=a,src=b); P16(dst=a,src=b).
// Net by 16-lane groups: a = [a0,a2,b0,b2], b = [a1,a3,b1,b3].  (HW-verified r12)
__device__ __forceinline__ void xchF(unsigned& a, unsigned& b) {
  asm volatile("v_permlane32_swap_b32 %0, %1" : "+v"(a), "+v"(b));
  asm volatile("v_permlane16_swap_b32 %0, %1" : "+v"(a), "+v"(b));
}

__global__ __launch_bounds__(256) void mha(
    const float* __restrict__ Qg, const float* __restrict__ Kg,
    const float* __restrict__ Vg, const void* __restrict__ maskg,
    const float* __restrict__ WQg, const float* __restrict__ bQg,
    const float* __restrict__ WKg, const float* __restrict__ bKg,
    const float* __restrict__ WVg, const float* __restrict__ bVg,
    const float* __restrict__ WOg, const float* __restrict__ bOg,
    float* __restrict__ outg)
{
  __shared__ __align__(16) short V2s[4][32*SV];   // per-wave V2t [d][j], j>=50 zeroed
  __shared__ unsigned sRawW[4][80];               // per-wave ballot-packed mask bits

  const int t = threadIdx.x;
  const int lane = t & 63;
  const int wv = t >> 6;
  const int c = lane & 15, g = lane >> 4;
  const int b = blockIdx.x*4 + wv;                // this wave's batch
  short* V2 = V2s[wv];
  unsigned* sRaw = sRawW[wv];

  auto mkfrag = [&](float4 x0, float4 x1) -> bf16x8 {
    const u32x4 u = {cvt2(x0.x,x0.y), cvt2(x0.z,x0.w), cvt2(x1.x,x1.y), cvt2(x1.z,x1.w)};
    return __builtin_bit_cast(bf16x8, u);
  };
  // W^T[dcol][g*8..g*8+7] fragment straight from global (L1-hot, same addrs all waves)
  auto ldW = [&](const float* __restrict__ Wp, int dcol) -> bf16x8 {
    float w[8];
    #pragma unroll
    for (int e = 0; e < 8; ++e) w[e] = Wp[(g*8 + e)*32 + dcol];
    const u32x4 u = {cvt2(w[0],w[1]), cvt2(w[2],w[3]), cvt2(w[4],w[5]), cvt2(w[6],w[7])};
    return __builtin_bit_cast(bf16x8, u);
  };
  // Y^T = W^T X^T (+bias); 2 xchF -> Y row as the next A/B fragment (HW-verified)
  auto projR = [&](bf16x8 xb, bf16x8 wa0, bf16x8 wa1,
                   float4 bv0, float4 bv1, float scale) -> bf16x8 {
    f32x4 c0 = {bv0.x, bv0.y, bv0.z, bv0.w};
    f32x4 c1 = {bv1.x, bv1.y, bv1.z, bv1.w};
    c0 = __builtin_amdgcn_mfma_f32_16x16x32_bf16(wa0, xb, c0, 0, 0, 0);
    c1 = __builtin_amdgcn_mfma_f32_16x16x32_bf16(wa1, xb, c1, 0, 0, 0);
    unsigned A0 = cvt2(c0[0]*scale, c0[1]*scale), A1 = cvt2(c0[2]*scale, c0[3]*scale);
    unsigned B0 = cvt2(c1[0]*scale, c1[1]*scale), B1 = cvt2(c1[2]*scale, c1[3]*scale);
    xchF(A0, B0); xchF(A1, B1);
    const u32x4 u = {A0, A1, B0, B1};
    return __builtin_bit_cast(bf16x8, u);
  };

  // ---- mask: width detect + 40 ballot chunks (batched 8-wide) -> per-wave sRaw ----
  {
    const unsigned wdet = ((const unsigned*)maskg)[lane];
    const bool byteMask = (__ballot(wdet > 1u) != 0ull);   // int32 0/1 words never >1
    for (int cg = 0; cg < 5; ++cg) {
      unsigned v[8];
      #pragma unroll
      for (int j = 0; j < 8; ++j) {
        const int idx = (cg*8 + j)*64 + lane;
        v[j] = 0;
        if (idx < 2500)
          v[j] = byteMask ? (unsigned)((const unsigned char*)maskg)[b*2500 + idx]
                          : ((const unsigned*)maskg)[b*2500 + idx];
      }
      #pragma unroll
      for (int j = 0; j < 8; ++j) {
        const unsigned long long m = __ballot(v[j] != 0u);
        const int ch = cg*8 + j;
        if (lane < 2) sRaw[ch*2 + lane] = lane ? (unsigned)(m >> 32) : (unsigned)m;
      }
    }
  }

  // ---- K phase: kf[0..3] fully in registers (pad rows clamp to row 0: finite) ----
  bf16x8 kf[4];
  {
    const bf16x8 wK0 = ldW(WKg, c), wK1 = ldW(WKg, 16 + c);
    const float4 bK0 = *(const float4*)&bKg[g*4];
    const float4 bK1 = *(const float4*)&bKg[16 + g*4];
    #pragma unroll
    for (int m = 0; m < 4; ++m) {
      const int row = m*16 + c;
      const int ra = b*1600 + ((row < 50) ? row : 0)*32 + g*8;
      const bf16x8 xb = mkfrag(*(const float4*)&Kg[ra], *(const float4*)&Kg[ra + 4]);
      const bf16x8 k1 = projR(xb, wK0, wK1, bK0, bK1, 1.f);
      kf[m] = projR(k1, wK0, wK1, bK0, bK1, 1.f);
    }
  }

  // ---- V phase: pass1 projR, pass2 normal orientation -> V2t LDS (j>=50 zeroed) ----
  {
    const bf16x8 wV0 = ldW(WVg, c), wV1 = ldW(WVg, 16 + c);
    const float4 bV0 = *(const float4*)&bVg[g*4];
    const float4 bV1 = *(const float4*)&bVg[16 + g*4];
    const float bc0 = bVg[c], bc1 = bVg[16 + c];
    #pragma unroll
    for (int m = 0; m < 4; ++m) {
      const int row = m*16 + c;
      const int ra = b*1600 + ((row < 50) ? row : 0)*32 + g*8;
      const bf16x8 xb = mkfrag(*(const float4*)&Vg[ra], *(const float4*)&Vg[ra + 4]);
      const bf16x8 v1 = projR(xb, wV0, wV1, bV0, bV1, 1.f);
      f32x4 z0 = {bc0, bc0, bc0, bc0}, z1 = {bc1, bc1, bc1, bc1};
      z0 = __builtin_amdgcn_mfma_f32_16x16x32_bf16(v1, wV0, z0, 0, 0, 0);
      z1 = __builtin_amdgcn_mfma_f32_16x16x32_bf16(v1, wV1, z1, 0, 0, 0);
      const int j0 = m*16 + g*4;
      const float a0 = (j0+0 < 50) ? z0[0] : 0.f;
      const float a1 = (j0+1 < 50) ? z0[1] : 0.f;
      const float a2 = (j0+2 < 50) ? z0[2] : 0.f;
      const float a3 = (j0+3 < 50) ? z0[3] : 0.f;
      *(uint2*)&V2[c*SV + j0] = make_uint2(cvt2(a0,a1), cvt2(a2,a3));
      const float u0 = (j0+0 < 50) ? z1[0] : 0.f;
      const float u1 = (j0+1 < 50) ? z1[1] : 0.f;
      const float u2 = (j0+2 < 50) ? z1[2] : 0.f;
      const float u3 = (j0+3 < 50) ? z1[3] : 0.f;
      *(uint2*)&V2[(16 + c)*SV + j0] = make_uint2(cvt2(u0,u1), cvt2(u2,u3));
    }
  }

  // ---- weights for Q and O hoisted; ONE real barrier makes all LDS visible ----
  const bf16x8 wQ0 = ldW(WQg, c), wQ1 = ldW(WQg, 16 + c);
  const float4 bQ0 = *(const float4*)&bQg[g*4];
  const float4 bQ1 = *(const float4*)&bQg[16 + g*4];
  const bf16x8 wO0 = ldW(WOg, c), wO1 = ldW(WOg, 16 + c);
  const float bO0 = bOg[c], bO1 = bOg[16 + c];
  __syncthreads();

  const bf16x8 zf = {0,0,0,0,0,0,0,0};

  #pragma unroll 1
  for (int qt = 0; qt < 4; ++qt) {
    const int myq = qt*16 + c;                 // this lane's q-row
    bf16x8 qb;
    {
      const int ra = b*1600 + ((myq < 50) ? myq : 0)*32 + g*8;
      const bf16x8 xq = mkfrag(*(const float4*)&Qg[ra], *(const float4*)&Qg[ra + 4]);
      const bf16x8 q1 = projR(xq, wQ0, wQ1, bQ0, bQ1, 1.f);
      qb = projR(q1, wQ0, wQ1, bQ0, bQ1, kQscale);
    }
    // per-lane mask words (funnel from sRaw)
    unsigned mm0, mm1;
    {
      const int bp = (myq < 50) ? 50*myq : 0;
      const unsigned ra = sRaw[(bp >> 5) + 0];
      const unsigned rb = sRaw[(bp >> 5) + 1];
      const unsigned rc = sRaw[(bp >> 5) + 2];
      const unsigned sh = bp & 31;
      mm0 = (unsigned)((((unsigned long long)rb << 32) | ra) >> sh);
      mm1 = (unsigned)((((unsigned long long)rc << 32) | rb) >> sh);
      if (myq >= 50) { mm0 = ~0u; mm1 = ~0u; }
    }
    // head loop: QK^T -> max-sub softmax -> xchF -> PV, P in registers
    unsigned ox0[4], ox1[4];
    #pragma unroll
    for (int h = 0; h < 4; ++h) {
      const bf16x8 vf0 = *(const bf16x8*)&V2[(h*8 + (c & 7))*SV + g*8];
      const bf16x8 vf1 = *(const bf16x8*)&V2[(h*8 + (c & 7))*SV + 32 + g*8];
      const bf16x8 qh = (g == h) ? qb : zf;    // zero non-head contraction slices
      f32x4 sc[4];
      #pragma unroll
      for (int Ni = 0; Ni < 4; ++Ni) {
        f32x4 z = {0.f, 0.f, 0.f, 0.f};
        sc[Ni] = __builtin_amdgcn_mfma_f32_16x16x32_bf16(kf[Ni], qh, z, 0, 0, 0);
      }
      // keep-mask + row max (kept scores only), then overflow-proof exp
      unsigned kpm = 0;
      float mx = -1e30f;
      #pragma unroll
      for (int Ni = 0; Ni < 4; ++Ni) {
        const unsigned w = (Ni < 2) ? mm0 : mm1;
        #pragma unroll
        for (int r = 0; r < 4; ++r) {
          const int key = Ni*16 + g*4 + r;
          const bool keep = (key < 50) && (((w >> (key & 31)) & 1u) == 0u);
          kpm |= keep ? (1u << (Ni*4 + r)) : 0u;
          mx = keep ? fmaxf(mx, sc[Ni][r]) : mx;
        }
      }
      mx = fmaxf(mx, __shfl_xor(mx, 16));
      mx = fmaxf(mx, __shfl_xor(mx, 32));
      float rs = 0.f;
      unsigned pk[8];
      #pragma unroll
      for (int Ni = 0; Ni < 4; ++Ni) {
        float p[4];
        #pragma unroll
        for (int r = 0; r < 4; ++r) {
          const float e = fexp2(sc[Ni][r] - mx);        // kept rows: <= 1
          p[r] = ((kpm >> (Ni*4 + r)) & 1u) ? e : 0.f;  // select kills masked/pad
          rs += p[r];
        }
        pk[Ni*2]   = cvt2(p[0], p[1]);
        pk[Ni*2+1] = cvt2(p[2], p[3]);
      }
      rs += __shfl_xor(rs, 16);
      rs += __shfl_xor(rs, 32);
      const float ri = (rs > 0.f) ? __builtin_amdgcn_rcpf(rs) : 0.f;  // finite always
      unsigned w0 = pk[0], w2 = pk[2];  xchF(w0, w2);
      unsigned w1 = pk[1], w3 = pk[3];  xchF(w1, w3);
      unsigned x0 = pk[4], x2 = pk[6];  xchF(x0, x2);
      unsigned x1 = pk[5], x3 = pk[7];  xchF(x1, x3);
      const u32x4 w0v = {w0, w1, w2, w3};
      const u32x4 w1v = {x0, x1, x2, x3};
      const bf16x8 pf0 = __builtin_bit_cast(bf16x8, w0v);
      const bf16x8 pf1 = __builtin_bit_cast(bf16x8, w1v);
      f32x4 cac = {0.f, 0.f, 0.f, 0.f};
      cac = __builtin_amdgcn_mfma_f32_16x16x32_bf16(vf0, pf0, cac, 0, 0, 0);
      cac = __builtin_amdgcn_mfma_f32_16x16x32_bf16(vf1, pf1, cac, 0, 0, 0);
      ox0[h] = cvt2(cac[0]*ri, cac[1]*ri);
      ox1[h] = cvt2(cac[2]*ri, cac[3]*ri);
    }
    // epilogue for this q-tile: xchF tree -> ctx A-frag; out = ctx@WO + bO + Q
    {
      float res[2][4];
      #pragma unroll
      for (int Nj = 0; Nj < 2; ++Nj)
        #pragma unroll
        for (int r = 0; r < 4; ++r) {
          const int row = qt*16 + g*4 + r;
          res[Nj][r] = (row < 50) ? Qg[b*1600 + row*32 + Nj*16 + c] : 0.f;
        }
      unsigned a0 = ox0[0], a1 = ox0[1], a2 = ox0[2], a3 = ox0[3];
      xchF(a0, a1);
      xchF(a2, a3);
      xchF(a0, a2);          // a0 = word0
      xchF(a1, a3);          // a1 = word2
      unsigned c0 = ox1[0], c1 = ox1[1], c2 = ox1[2], c3 = ox1[3];
      xchF(c0, c1);
      xchF(c2, c3);
      xchF(c0, c2);          // c0 = word1
      xchF(c1, c3);          // c1 = word3
      const u32x4 afv = {a0, c0, a1, c1};
      const bf16x8 af = __builtin_bit_cast(bf16x8, afv);
      #pragma unroll
      for (int Nj = 0; Nj < 2; ++Nj) {
        const bf16x8 bbf = Nj ? wO1 : wO0;
        const float bv = Nj ? bO1 : bO0;
        f32x4 o = {bv, bv, bv, bv};
        o = __builtin_amdgcn_mfma_f32_16x16x32_bf16(af, bbf, o, 0, 0, 0);
        #pragma unroll
        for (int r = 0; r < 4; ++r) {
          const int row = qt*16 + g*4 + r;
          if (row < 50)
            outg[b*1600 + row*32 + Nj*16 + c] = o[r] + res[Nj][r];
        }
      }
    }
  }
}

extern "C" void kernel_launch(void* const* d_in, const int* in_sizes, int n_in,
                              void* d_out, int out_size, void* d_ws, size_t ws_size,
                              hipStream_t stream) {
  const float* Q  = (const float*)d_in[0];
  const float* K  = (const float*)d_in[1];
  const float* V  = (const float*)d_in[2];
  const void*  M  = d_in[3];
  const float* WQ = (const float*)d_in[4];
  const float* bQ = (const float*)d_in[5];
  const float* WK = (const float*)d_in[6];
  const float* bK = (const float*)d_in[7];
  const float* WV = (const float*)d_in[8];
  const float* bV = (const float*)d_in[9];
  const float* WO = (const float*)d_in[10];
  const float* bO = (const float*)d_in[11];
  float* out = (float*)d_out;
  (void)d_ws; (void)ws_size; (void)in_sizes; (void)n_in; (void)out_size;

  hipLaunchKernelGGL(mha, dim3(NB/4), dim3(256), 0, stream,
                     Q, K, V, M, WQ, bQ, WK, bK, WV, bV, WO, bO, out);
}

// Round 16
// 56.061 us; speedup vs baseline: 1.1607x; 1.1607x over previous
//
#include <hip/hip_runtime.h>

// B=4096, S=50, D=32, H=4, HD=8. One block = one batch, 256 threads, wave = 16-row tile.
// ONE barrier. W/bias fragments direct from global (L1-hot, r15-verified); projection
// chains in registers (projR layout == MFMA A/B fragment, r12/r13-verified); LDS holds
// only K2 + V2t + mask ballots (~10 KB). Softmax with max-subtraction (finite by design).
#define NB 4096
// fold 1/sqrt(8)*log2(e) into q: softmax uses raw v_exp_f32 (=2^x)
constexpr float kQscale = 0.35355339059327378f * 1.4426950408889634f;
constexpr int ST = 40;     // K2 stride (shorts)
constexpr int SV = 72;     // V2t stride [d][j] (shorts)

typedef __attribute__((ext_vector_type(8))) short bf16x8;
typedef __attribute__((ext_vector_type(4))) float f32x4;
typedef __attribute__((ext_vector_type(4))) unsigned u32x4;

__device__ __forceinline__ unsigned cvt2(float lo, float hi) {  // 2xf32 -> packed bf16 RNE
  unsigned u;
  asm("v_cvt_pk_bf16_f32 %0, %1, %2" : "=v"(u) : "v"(lo), "v"(hi));
  return u;
}
__device__ __forceinline__ float fexp2(float x) {               // 2^x, 1 inst
  float r;
  asm("v_exp_f32 %0, %1" : "=v"(r) : "v"(x));
  return r;
}
// xchF(a,b): P32(dst=a,src=b); P16(dst=a,src=b).
// Net by 16-lane groups: a = [a0,a2,b0,b2], b = [a1,a3,b1,b3].  (HW-verified r12)
__device__ __forceinline__ void xchF(unsigned& a, unsigned& b) {
  asm volatile("v_permlane32_swap_b32 %0, %1" : "+v"(a), "+v"(b));
  asm volatile("v_permlane16_swap_b32 %0, %1" : "+v"(a), "+v"(b));
}

__global__ __launch_bounds__(256) void mha(
    const float* __restrict__ Qg, const float* __restrict__ Kg,
    const float* __restrict__ Vg, const void* __restrict__ maskg,
    const float* __restrict__ WQg, const float* __restrict__ bQg,
    const float* __restrict__ WKg, const float* __restrict__ bKg,
    const float* __restrict__ WVg, const float* __restrict__ bVg,
    const float* __restrict__ WOg, const float* __restrict__ bOg,
    float* __restrict__ outg)
{
  __shared__ __align__(16) short K2s[64*ST];   // 5120 B
  __shared__ __align__(16) short V2[32*SV];    // 4608 B, cols j>=50 zeroed
  __shared__ unsigned sRaw[80];                // 320 B ballot-packed mask bits

  const int t = threadIdx.x;
  const int b = blockIdx.x;
  const int lane = t & 63;
  const int wv = t >> 6;
  const int c = lane & 15, g = lane >> 4;
  const int myrow = wv*16 + c;                 // the [s]-row / q-row this lane owns

  auto mkfrag = [&](float4 x0, float4 x1) -> bf16x8 {
    const u32x4 u = {cvt2(x0.x,x0.y), cvt2(x0.z,x0.w), cvt2(x1.x,x1.y), cvt2(x1.z,x1.w)};
    return __builtin_bit_cast(bf16x8, u);
  };
  // W^T[dcol][g*8..g*8+7] fragment straight from global (L1-hot, same addrs all blocks)
  auto ldW = [&](const float* __restrict__ Wp, int dcol) -> bf16x8 {
    float w[8];
    #pragma unroll
    for (int e = 0; e < 8; ++e) w[e] = Wp[(g*8 + e)*32 + dcol];
    const u32x4 u = {cvt2(w[0],w[1]), cvt2(w[2],w[3]), cvt2(w[4],w[5]), cvt2(w[6],w[7])};
    return __builtin_bit_cast(bf16x8, u);
  };
  // Y^T = W^T X^T (+bias); 2 xchF -> Y row as the next A/B fragment (HW-verified)
  auto projR = [&](bf16x8 xb, bf16x8 wa0, bf16x8 wa1,
                   float4 bv0, float4 bv1, float scale) -> bf16x8 {
    f32x4 c0 = {bv0.x, bv0.y, bv0.z, bv0.w};
    f32x4 c1 = {bv1.x, bv1.y, bv1.z, bv1.w};
    c0 = __builtin_amdgcn_mfma_f32_16x16x32_bf16(wa0, xb, c0, 0, 0, 0);
    c1 = __builtin_amdgcn_mfma_f32_16x16x32_bf16(wa1, xb, c1, 0, 0, 0);
    unsigned A0 = cvt2(c0[0]*scale, c0[1]*scale), A1 = cvt2(c0[2]*scale, c0[3]*scale);
    unsigned B0 = cvt2(c1[0]*scale, c1[1]*scale), B1 = cvt2(c1[2]*scale, c1[3]*scale);
    xchF(A0, B0); xchF(A1, B1);
    const u32x4 u = {A0, A1, B0, B1};
    return __builtin_bit_cast(bf16x8, u);
  };

  // ---- phase A (no barrier): raw loads, mask ballots, K/V/Q chains ----
  const int ra = b*1600 + ((myrow < 50) ? myrow : 0)*32 + g*8;  // pad rows clamp to 0
  const bf16x8 xbK = mkfrag(*(const float4*)&Kg[ra], *(const float4*)&Kg[ra + 4]);
  const bf16x8 xbV = mkfrag(*(const float4*)&Vg[ra], *(const float4*)&Vg[ra + 4]);
  const bf16x8 xbQ = mkfrag(*(const float4*)&Qg[ra], *(const float4*)&Qg[ra + 4]);

  {  // mask: width detect + 10 ballot chunks per wave -> sRaw
    const unsigned wdet = ((const unsigned*)maskg)[lane];
    const bool byteMask = (__ballot(wdet > 1u) != 0ull);   // int32 0/1 words never >1
    #pragma unroll
    for (int cc = 0; cc < 10; ++cc) {
      const int ch = wv*10 + cc;
      const int idx = ch*64 + lane;
      unsigned val = 0;
      if (idx < 2500)
        val = byteMask ? (unsigned)((const unsigned char*)maskg)[b*2500 + idx]
                       : ((const unsigned*)maskg)[b*2500 + idx];
      const unsigned long long m = __ballot(val != 0u);
      if (lane < 2) sRaw[ch*2 + lane] = lane ? (unsigned)(m >> 32) : (unsigned)m;
    }
  }

  {  // K chain: pass1 in regs, pass2 -> K2 LDS (own 16 rows, packed b64)
    const bf16x8 wK0 = ldW(WKg, c), wK1 = ldW(WKg, 16 + c);
    const float4 bK0 = *(const float4*)&bKg[g*4];
    const float4 bK1 = *(const float4*)&bKg[16 + g*4];
    const bf16x8 k1 = projR(xbK, wK0, wK1, bK0, bK1, 1.f);
    #pragma unroll
    for (int Ni = 0; Ni < 2; ++Ni) {
      const bf16x8 wa = Ni ? wK1 : wK0;
      const float4 bv = Ni ? bK1 : bK0;
      f32x4 acc = {bv.x, bv.y, bv.z, bv.w};
      acc = __builtin_amdgcn_mfma_f32_16x16x32_bf16(wa, k1, acc, 0, 0, 0);
      *(uint2*)&K2s[myrow*ST + Ni*16 + g*4] =
          make_uint2(cvt2(acc[0], acc[1]), cvt2(acc[2], acc[3]));
    }
  }
  {  // V chain: pass1 projR, pass2 normal orientation -> V2t LDS (j>=50 zeroed)
    const bf16x8 wV0 = ldW(WVg, c), wV1 = ldW(WVg, 16 + c);
    const float4 bV0 = *(const float4*)&bVg[g*4];
    const float4 bV1 = *(const float4*)&bVg[16 + g*4];
    const float bc0 = bVg[c], bc1 = bVg[16 + c];
    const bf16x8 v1 = projR(xbV, wV0, wV1, bV0, bV1, 1.f);
    f32x4 z0 = {bc0, bc0, bc0, bc0}, z1 = {bc1, bc1, bc1, bc1};
    z0 = __builtin_amdgcn_mfma_f32_16x16x32_bf16(v1, wV0, z0, 0, 0, 0);
    z1 = __builtin_amdgcn_mfma_f32_16x16x32_bf16(v1, wV1, z1, 0, 0, 0);
    const int j0 = wv*16 + g*4;
    const float a0 = (j0+0 < 50) ? z0[0] : 0.f;
    const float a1 = (j0+1 < 50) ? z0[1] : 0.f;
    const float a2 = (j0+2 < 50) ? z0[2] : 0.f;
    const float a3 = (j0+3 < 50) ? z0[3] : 0.f;
    *(uint2*)&V2[c*SV + j0] = make_uint2(cvt2(a0,a1), cvt2(a2,a3));
    const float u0 = (j0+0 < 50) ? z1[0] : 0.f;
    const float u1 = (j0+1 < 50) ? z1[1] : 0.f;
    const float u2 = (j0+2 < 50) ? z1[2] : 0.f;
    const float u3 = (j0+3 < 50) ? z1[3] : 0.f;
    *(uint2*)&V2[(16 + c)*SV + j0] = make_uint2(cvt2(u0,u1), cvt2(u2,u3));
  }
  bf16x8 qb;
  {  // Q chain fully in regs (scale incl. log2e)
    const bf16x8 wQ0 = ldW(WQg, c), wQ1 = ldW(WQg, 16 + c);
    const float4 bQ0 = *(const float4*)&bQg[g*4];
    const float4 bQ1 = *(const float4*)&bQg[16 + g*4];
    const bf16x8 q1 = projR(xbQ, wQ0, wQ1, bQ0, bQ1, 1.f);
    qb = projR(q1, wQ0, wQ1, bQ0, bQ1, kQscale);
  }
  __syncthreads();   // the ONLY barrier: K2, V2t, sRaw all visible

  // ---- per-lane mask words (funnel from sRaw); K2 A-fragments ----
  unsigned mm0, mm1;
  {
    const int bp = (myrow < 50) ? 50*myrow : 0;
    const unsigned fa = sRaw[(bp >> 5) + 0];
    const unsigned fb = sRaw[(bp >> 5) + 1];
    const unsigned fc = sRaw[(bp >> 5) + 2];
    const unsigned sh = bp & 31;
    mm0 = (unsigned)((((unsigned long long)fb << 32) | fa) >> sh);
    mm1 = (unsigned)((((unsigned long long)fc << 32) | fb) >> sh);
    if (myrow >= 50) { mm0 = ~0u; mm1 = ~0u; }
  }
  bf16x8 kf[4];
  #pragma unroll
  for (int Ni = 0; Ni < 4; ++Ni)
    kf[Ni] = *(const bf16x8*)&K2s[(Ni*16 + c)*ST + g*8];

  // ---- head loop: QK^T -> max-sub softmax -> xchF -> PV, P in registers ----
  const bf16x8 zf = {0,0,0,0,0,0,0,0};
  unsigned ox0[4], ox1[4];
  #pragma unroll
  for (int h = 0; h < 4; ++h) {
    const bf16x8 vf0 = *(const bf16x8*)&V2[(h*8 + (c & 7))*SV + g*8];
    const bf16x8 vf1 = *(const bf16x8*)&V2[(h*8 + (c & 7))*SV + 32 + g*8];
    const bf16x8 qh = (g == h) ? qb : zf;    // zero non-head contraction slices
    f32x4 sc[4];
    #pragma unroll
    for (int Ni = 0; Ni < 4; ++Ni) {
      f32x4 z = {0.f, 0.f, 0.f, 0.f};
      sc[Ni] = __builtin_amdgcn_mfma_f32_16x16x32_bf16(kf[Ni], qh, z, 0, 0, 0);
    }
    unsigned kpm = 0;
    float mx = -1e30f;
    #pragma unroll
    for (int Ni = 0; Ni < 4; ++Ni) {
      const unsigned w = (Ni < 2) ? mm0 : mm1;
      #pragma unroll
      for (int r = 0; r < 4; ++r) {
        const int key = Ni*16 + g*4 + r;
        const bool keep = (key < 50) && (((w >> (key & 31)) & 1u) == 0u);
        kpm |= keep ? (1u << (Ni*4 + r)) : 0u;
        mx = keep ? fmaxf(mx, sc[Ni][r]) : mx;
      }
    }
    mx = fmaxf(mx, __shfl_xor(mx, 16));
    mx = fmaxf(mx, __shfl_xor(mx, 32));
    float rs = 0.f;
    unsigned pk[8];
    #pragma unroll
    for (int Ni = 0; Ni < 4; ++Ni) {
      float p[4];
      #pragma unroll
      for (int r = 0; r < 4; ++r) {
        const float e = fexp2(sc[Ni][r] - mx);        // kept: <= 1, overflow-proof
        p[r] = ((kpm >> (Ni*4 + r)) & 1u) ? e : 0.f;  // select kills masked/pad
        rs += p[r];
      }
      pk[Ni*2]   = cvt2(p[0], p[1]);
      pk[Ni*2+1] = cvt2(p[2], p[3]);
    }
    rs += __shfl_xor(rs, 16);
    rs += __shfl_xor(rs, 32);
    const float ri = (rs > 0.f) ? __builtin_amdgcn_rcpf(rs) : 0.f;  // finite always
    unsigned w0 = pk[0], w2 = pk[2];  xchF(w0, w2);
    unsigned w1 = pk[1], w3 = pk[3];  xchF(w1, w3);
    unsigned x0 = pk[4], x2 = pk[6];  xchF(x0, x2);
    unsigned x1 = pk[5], x3 = pk[7];  xchF(x1, x3);
    const u32x4 w0v = {w0, w1, w2, w3};
    const u32x4 w1v = {x0, x1, x2, x3};
    const bf16x8 pf0 = __builtin_bit_cast(bf16x8, w0v);
    const bf16x8 pf1 = __builtin_bit_cast(bf16x8, w1v);
    f32x4 cac = {0.f, 0.f, 0.f, 0.f};
    cac = __builtin_amdgcn_mfma_f32_16x16x32_bf16(vf0, pf0, cac, 0, 0, 0);
    cac = __builtin_amdgcn_mfma_f32_16x16x32_bf16(vf1, pf1, cac, 0, 0, 0);
    ox0[h] = cvt2(cac[0]*ri, cac[1]*ri);
    ox1[h] = cvt2(cac[2]*ri, cac[3]*ri);
  }

  // ---- epilogue: xchF tree -> ctx A-frag; out = ctx@WO + bO + Q ----
  {
    float res[2][4];
    #pragma unroll
    for (int Nj = 0; Nj < 2; ++Nj)
      #pragma unroll
      for (int r = 0; r < 4; ++r) {
        const int row = wv*16 + g*4 + r;
        res[Nj][r] = (row < 50) ? Qg[b*1600 + row*32 + Nj*16 + c] : 0.f;
      }
    unsigned a0 = ox0[0], a1 = ox0[1], a2 = ox0[2], a3 = ox0[3];
    xchF(a0, a1);
    xchF(a2, a3);
    xchF(a0, a2);          // a0 = word0
    xchF(a1, a3);          // a1 = word2
    unsigned c0 = ox1[0], c1 = ox1[1], c2 = ox1[2], c3 = ox1[3];
    xchF(c0, c1);
    xchF(c2, c3);
    xchF(c0, c2);          // c0 = word1
    xchF(c1, c3);          // c1 = word3
    const u32x4 afv = {a0, c0, a1, c1};
    const bf16x8 af = __builtin_bit_cast(bf16x8, afv);
    const bf16x8 wO0 = ldW(WOg, c), wO1 = ldW(WOg, 16 + c);
    const float bO0 = bOg[c], bO1 = bOg[16 + c];
    #pragma unroll
    for (int Nj = 0; Nj < 2; ++Nj) {
      const bf16x8 bbf = Nj ? wO1 : wO0;
      const float bv = Nj ? bO1 : bO0;
      f32x4 o = {bv, bv, bv, bv};
      o = __builtin_amdgcn_mfma_f32_16x16x32_bf16(af, bbf, o, 0, 0, 0);
      #pragma unroll
      for (int r = 0; r < 4; ++r) {
        const int row = wv*16 + g*4 + r;
        if (row < 50)
          outg[b*1600 + row*32 + Nj*16 + c] = o[r] + res[Nj][r];
      }
    }
  }
}

extern "C" void kernel_launch(void* const* d_in, const int* in_sizes, int n_in,
                              void* d_out, int out_size, void* d_ws, size_t ws_size,
                              hipStream_t stream) {
  const float* Q  = (const float*)d_in[0];
  const float* K  = (const float*)d_in[1];
  const float* V  = (const float*)d_in[2];
  const void*  M  = d_in[3];
  const float* WQ = (const float*)d_in[4];
  const float* bQ = (const float*)d_in[5];
  const float* WK = (const float*)d_in[6];
  const float* bK = (const float*)d_in[7];
  const float* WV = (const float*)d_in[8];
  const float* bV = (const float*)d_in[9];
  const float* WO = (const float*)d_in[10];
  const float* bO = (const float*)d_in[11];
  float* out = (float*)d_out;
  (void)d_ws; (void)ws_size; (void)in_sizes; (void)n_in; (void)out_size;

  hipLaunchKernelGGL(mha, dim3(NB), dim3(256), 0, stream,
                     Q, K, V, M, WQ, bQ, WK, bK, WV, bV, WO, bO, out);
}